// Round 9
// baseline (257.916 us; speedup 1.0000x reference)
//
#include <hip/hip_runtime.h>

typedef __attribute__((ext_vector_type(8))) short short8;
typedef __attribute__((ext_vector_type(4))) float f32x4;
typedef __attribute__((ext_vector_type(2))) float f32x2;

constexpr int CIN  = 256;
constexpr int HWp  = 16384;        // H*W
constexpr int NSEL = 65536;
constexpr int NCOLS = 2056;

// out offsets (elements)
constexpr size_t OUT_PL   = (size_t)NSEL * NCOLS;  // pseudo_labels
constexpr size_t OUT_LOSS = OUT_PL + NSEL;         // sal_loss
constexpr size_t OUT_NQ   = OUT_LOSS + 1;          // new_queue

// ws offsets (bytes)
constexpr size_t WS_TILECNT  = 0;        // 256 int
constexpr size_t WS_TILEBASE = 2048;     // 256 int
constexpr size_t WS_NPOS     = 4096;     // int
constexpr size_t WS_LPLN     = 4104;     // 2 float
constexpr size_t WS_WQT      = 8192;     // 8192 f  (W_q transposed [256][32])
constexpr size_t WS_WKMT     = 40960;    // 8192 f  (momentum W_k transposed)
constexpr size_t WS_PSUM     = 73728;    // 256 f   (proto sums, atomically built)
constexpr size_t WS_PROTO    = 74752;    // 256 f   (normalized protos [8][32])
constexpr size_t WS_QT       = 131072;   // 65536 ushort (queue^T bf16 [2048][32])
constexpr size_t WS_CLSEL    = 262144;   // 65536 f
constexpr size_t WS_SALSEL   = 524288;   // 65536 int
constexpr size_t WS_QSEL     = 1048576;  // 65536*32 ushort (q_sel bf16)

static __device__ __forceinline__ unsigned short f2bf(float f) {
  const unsigned x = __float_as_uint(f);
  return (unsigned short)((x + 0x7fffu + ((x >> 16) & 1u)) >> 16);
}
static __device__ __forceinline__ float bf2f(unsigned short u) {
  return __uint_as_float(((unsigned)u) << 16);
}

// ---- P1: per-512-pixel-tile fg counts; blocks 0..31 also build transposed weights ----
__global__ __launch_bounds__(256) void kP1(const int* __restrict__ salq, int* __restrict__ tileCnt,
                                           const float* __restrict__ Wq, const float* __restrict__ Wk,
                                           float* __restrict__ wqt, float* __restrict__ wkmt,
                                           float* __restrict__ psum, float* __restrict__ lpln) {
  const int g = blockIdx.x, t = threadIdx.x;
  __shared__ int red[256];
  const int base = g << 9;
  red[t] = ((salq[base + 2 * t] != 0) ? 1 : 0) + ((salq[base + 2 * t + 1] != 0) ? 1 : 0);
  __syncthreads();
  for (int s = 128; s > 0; s >>= 1) { if (t < s) red[t] += red[t + s]; __syncthreads(); }
  if (t == 0) tileCnt[g] = red[0];
  if (g < 32) {
    const int idx = (g << 8) + t;
    const int o = idx & 31, c = idx >> 5;
    const float wq = Wq[o * 256 + c];
    wqt[idx] = wq;
    wkmt[idx] = 0.999f * Wk[o * 256 + c] + 0.001f * wq;
  }
  if (g == 32) { psum[t] = 0.f; if (t < 2) lpln[t] = 0.f; }
}

// ---- P2: exclusive scan of 256 tile counts ----
__global__ __launch_bounds__(256) void kP2(const int* __restrict__ tileCnt, int* __restrict__ tileBase,
                                           int* __restrict__ nposp) {
  const int t = threadIdx.x;
  __shared__ int sc[256];
  const int c0 = tileCnt[t];
  sc[t] = c0;
  __syncthreads();
  for (int off = 1; off < 256; off <<= 1) {
    int v = (t >= off) ? sc[t - off] : 0;
    __syncthreads();
    sc[t] += v;
    __syncthreads();
  }
  tileBase[t] = sc[t] - c0;
  if (t == 255) *nposp = sc[255];
}

// ---- AB: both conv passes, 2 px/thread. blocks 0..255: im_q; 256..511: im_k ----
__global__ __launch_bounds__(256) void kAB(
    const float* __restrict__ imq, const float* __restrict__ imk,
    const int* __restrict__ salq, const int* __restrict__ salk,
    const float* __restrict__ wqt, const float* __restrict__ wkmt,
    const float* __restrict__ wbg, const float* __restrict__ wcls,
    const int* __restrict__ tileBase,
    ushort* __restrict__ qsel, float* __restrict__ clsel, int* __restrict__ salsel,
    float* __restrict__ lpln, float* __restrict__ psum) {
  const int g = blockIdx.x, t = threadIdx.x;
  const bool isA = (g < 256);
  const int tile = isA ? g : (g - 256);
  const int base = tile << 9;            // 512 px per tile
  const int b = base >> 14;
  const int n = (base & (HWp - 1)) + (t << 1);
  const float* __restrict__ ip = (isA ? imq : imk) + (size_t)b * (CIN * HWp) + n;
  const float* __restrict__ wt0 = isA ? wqt : wkmt;

  float a0[32], a1[32];
#pragma unroll
  for (int o = 0; o < 32; ++o) { a0[o] = 0.f; a1[o] = 0.f; }
  float bg0 = 0.f, bg1 = 0.f;

#pragma unroll 8
  for (int c = 0; c < 256; ++c) {
    const f32x2 v = __builtin_nontemporal_load(
        reinterpret_cast<const f32x2*>(ip + (size_t)c * HWp));
    const float* wt = wt0 + (c << 5);
    const float wb = wbg[c];
#pragma unroll
    for (int o = 0; o < 32; ++o) {
      a0[o] = fmaf(wt[o], v.x, a0[o]);
      a1[o] = fmaf(wt[o], v.y, a1[o]);
    }
    bg0 = fmaf(wb, v.x, bg0);
    bg1 = fmaf(wb, v.y, bg1);
  }

  const int lane = t & 63, wv = t >> 6;
  const int flat0 = base + (t << 1);

  if (isA) {
    const int s0 = (salq[flat0] != 0) ? 1 : 0;
    const int s1 = (salq[flat0 + 1] != 0) ? 1 : 0;
    const unsigned spair = (unsigned)(s0 + s1);
    // block-wide exclusive prefix over thread fg-counts (flat order = pixel order)
    unsigned incl = spair;
#pragma unroll
    for (int off = 1; off < 64; off <<= 1) {
      unsigned u = __shfl_up(incl, off);
      if (lane >= off) incl += u;
    }
    __shared__ int wtot[4];
    if (lane == 63) wtot[wv] = (int)incl;
    __syncthreads();
    int wbase = 0;
    for (int i = 0; i < wv; ++i) wbase += wtot[i];
    const int excl = tileBase[tile] + wbase + (int)(incl - spair);

#pragma unroll
    for (int i = 0; i < 2; ++i) {
      const int si = i ? s1 : s0;
      const int rank = i ? (excl + s0) : excl;
      if (si && rank < NSEL) {
        float ss = 0.f;
#pragma unroll
        for (int o = 0; o < 32; ++o) { const float a = i ? a1[o] : a0[o]; ss = fmaf(a, a, ss); }
        const float inv = 1.f / fmaxf(sqrtf(ss), 1e-12f);
        float qn[32];
#pragma unroll
        for (int o = 0; o < 32; ++o) qn[o] = (i ? a1[o] : a0[o]) * inv;
        float m = -3.402823466e38f;
#pragma unroll
        for (int j = 0; j < 20; ++j) {
          float d = 0.f;
#pragma unroll
          for (int o = 0; o < 32; ++o) d = fmaf(wcls[(j << 5) + o], qn[o], d);
          m = fmaxf(m, d);
        }
        clsel[rank] = m;
        salsel[rank] = b;
        ushort* qp = qsel + ((size_t)rank << 5);
#pragma unroll
        for (int v4 = 0; v4 < 4; ++v4) {
          short8 v8;
#pragma unroll
          for (int j = 0; j < 8; ++j) v8[j] = (short)f2bf(qn[(v4 << 3) + j]);
          *reinterpret_cast<short8*>(qp + (v4 << 3)) = v8;
        }
      }
    }
    // balanced BCE partials
    const float gz0 = (bg0 >= 0.f) ? 1.f : 0.f;
    const float gz1 = (bg1 >= 0.f) ? 1.f : 0.f;
    const float lv0 = bg0 * ((float)s0 - gz0) - log1pf(expf(bg0 - 2.f * bg0 * gz0));
    const float lv1 = bg1 * ((float)s1 - gz1) - log1pf(expf(bg1 - 2.f * bg1 * gz1));
    float lp = -(s0 ? lv0 : 0.f) - (s1 ? lv1 : 0.f);
    float ln = -(s0 ? 0.f : lv0) - (s1 ? 0.f : lv1);
#pragma unroll
    for (int off = 32; off > 0; off >>= 1) { lp += __shfl_down(lp, off); ln += __shfl_down(ln, off); }
    __shared__ float slp[4], sln[4];
    if (lane == 0) { slp[wv] = lp; sln[wv] = ln; }
    __syncthreads();
    if (t == 0) {
      atomicAdd(&lpln[0], slp[0] + slp[1] + slp[2] + slp[3]);
      atomicAdd(&lpln[1], sln[0] + sln[1] + sln[2] + sln[3]);
    }
  } else {
    const int s0 = (salk[flat0] != 0) ? 1 : 0;
    const int s1 = (salk[flat0 + 1] != 0) ? 1 : 0;
    float ss0 = 0.f, ss1 = 0.f;
#pragma unroll
    for (int o = 0; o < 32; ++o) { ss0 = fmaf(a0[o], a0[o], ss0); ss1 = fmaf(a1[o], a1[o], ss1); }
    const float inv0 = s0 ? (1.f / fmaxf(sqrtf(ss0), 1e-12f)) : 0.f;
    const float inv1 = s1 ? (1.f / fmaxf(sqrtf(ss1), 1e-12f)) : 0.f;
    float p[32];
#pragma unroll
    for (int o = 0; o < 32; ++o) p[o] = a0[o] * inv0 + a1[o] * inv1;
#pragma unroll
    for (int o = 0; o < 32; ++o) {
#pragma unroll
      for (int off = 32; off > 0; off >>= 1) p[o] += __shfl_down(p[o], off);
    }
    __shared__ float sp[4][32];
    if (lane == 0) {
#pragma unroll
      for (int o = 0; o < 32; ++o) sp[wv][o] = p[o];
    }
    __syncthreads();
    if (t < 32) atomicAdd(&psum[(b << 5) + t], sp[0][t] + sp[1][t] + sp[2][t] + sp[3][t]);
  }
}

// ---- C: fused. Block 256: proto normalize + loss + new_queue head cols.
//      Blocks 0..255: bf16 queue transpose + new_queue tail copy. ----
__global__ __launch_bounds__(256) void kC(const float* __restrict__ objq, const float* __restrict__ psum,
                                          const float* __restrict__ lpln, const int* __restrict__ nposp,
                                          float* __restrict__ proto, ushort* __restrict__ qt,
                                          float* __restrict__ nq, float* __restrict__ outLoss) {
  const int g = blockIdx.x, t = threadIdx.x;
  if (g == 256) {
    __shared__ float sq[256];
    __shared__ float sinv[8];
    const float v = psum[t];
    sq[t] = v * v;
    __syncthreads();
    if (t < 8) {
      float s = 0.f;
      for (int o = 0; o < 32; ++o) s += sq[(t << 5) + o];
      sinv[t] = 1.f / fmaxf(sqrtf(s), 1e-12f);
    }
    __syncthreads();
    const float pv = v * sinv[t >> 5];
    proto[t] = pv;                           // t = p*32 + o
    const int p = t >> 5, o = t & 31;
    nq[(size_t)o * 2048 + p] = pv;           // new_queue head (first 8 cols)
    if (t == 0) {
      const float np = (float)(*nposp);
      outLoss[0] = ((131072.f - np) / 131072.f * lpln[0] + np / 131072.f * lpln[1]) / 131072.f;
    }
  } else {
    const int idx = (g << 8) + t;
    const int o = idx >> 11, j = idx & 2047;
    const float v = objq[idx];
    qt[(j << 5) + o] = f2bf(v);              // bank logits use the OLD queue
    if (j >= 8) nq[idx] = v;
  }
}

// ---- DE: logits. Block = 16 rows (grid 4096). 8 column chunks of 256 cols,
// double-buffered LDS (~34 KB -> 4 blocks/CU). Steady-state interval:
//   {prefetch next qt frags (loads FIRST so waitcnt needn't drain stores),
//    drain chunk c-1 (1KB-contiguous row stores), compute chunk c -> other buf}
// one barrier per interval -> store latency hides under MFMA + 3 other blocks.
__global__ __launch_bounds__(256) void kDE(const ushort* __restrict__ qsel, const ushort* __restrict__ qt,
                                           const float* __restrict__ proto, const float* __restrict__ clsel,
                                           const int* __restrict__ salsel,
                                           float* __restrict__ out, int* __restrict__ pl) {
  __shared__ float buf[2][16][260];  // 2 x 16 rows x 256 cols (+4 pad)
  __shared__ float dd[16][9];
  __shared__ float hd[16][8];
  const int t = threadIdx.x, g = blockIdx.x;
  const int wv = t >> 6, lane = t & 63;
  const int r0 = g << 4;            // 16 rows per block
  if (t < 16) pl[r0 + t] = 0;

  const int rlo = lane & 15, kh = lane >> 4;
  const f32x4 zero = {0.f, 0.f, 0.f, 0.f};

  // B-fragment: the block's 16 q_sel rows (reused for all chunks)
  const short8 bfrag = *reinterpret_cast<const short8*>(
      qsel + (size_t)(r0 + rlo) * 32 + kh * 8);
  const ushort* qa = qt + rlo * 32 + kh * 8;
  float* obase = out + (size_t)r0 * NCOLS;

  // head dots: 128 threads, row = t>>3, proto = t&7
  if (t < 128) {
    const int ri = t >> 3, pp = t & 7;
    const short8* qp = reinterpret_cast<const short8*>(qsel + ((size_t)(r0 + ri) << 5));
    float s = 0.f;
#pragma unroll
    for (int i = 0; i < 4; ++i) {
      const short8 v8 = qp[i];
#pragma unroll
      for (int j = 0; j < 8; ++j)
        s = fmaf(proto[(pp << 5) + (i << 3) + j], bf2f((unsigned short)v8[j]), s);
    }
    dd[ri][pp] = s;
  }
  __syncthreads();
  if (t < 16) {
    const int b = salsel[r0 + t];
    hd[t][0] = clsel[r0 + t] * 2.5f;
#pragma unroll
    for (int c = 0; c < 7; ++c) {
      const int pi = c + ((c >= b) ? 1 : 0);
      hd[t][1 + c] = dd[t][pi] * 2.5f;
    }
  }

  // prologue: load chunk 0 frags, compute chunk 0 -> buf[0]
  short8 af[4];
#pragma unroll
  for (int i = 0; i < 4; ++i)
    af[i] = *reinterpret_cast<const short8*>(qa + (size_t)((wv << 2) + i) * 512);
#pragma unroll
  for (int i = 0; i < 4; ++i) {
    f32x4 r = __builtin_amdgcn_mfma_f32_16x16x32_bf16(af[i], bfrag, zero, 0, 0, 0);
    r *= 2.5f;
    *reinterpret_cast<f32x4*>(&buf[0][rlo][(((wv << 2) + i) << 4) + (kh << 2)]) = r;
  }
  __syncthreads();

  for (int c = 1; c < 8; ++c) {
    const int pb = (c - 1) & 1, cb = c & 1;
    // 1) prefetch chunk c frags (global loads issued before any stores)
#pragma unroll
    for (int i = 0; i < 4; ++i)
      af[i] = *reinterpret_cast<const short8*>(qa + (size_t)((c << 4) + (wv << 2) + i) * 512);
    // 2) drain chunk c-1: wave wv writes rows {wv,4+wv,8+wv,12+wv}, 1KB each
    if (c == 1 && t < 32) {
      const int rr = t >> 1, cc = (t & 1) << 2;
      *reinterpret_cast<f32x4*>(obase + (size_t)rr * NCOLS + cc) =
          *reinterpret_cast<const f32x4*>(&hd[rr][cc]);
    }
#pragma unroll
    for (int it = 0; it < 4; ++it) {
      const int row = (it << 2) + wv;
      const f32x4 v = *reinterpret_cast<const f32x4*>(&buf[pb][row][lane << 2]);
      *reinterpret_cast<f32x4*>(obase + (size_t)row * NCOLS + 8 + ((c - 1) << 8) + (lane << 2)) = v;
    }
    // 3) compute chunk c into the other buffer
#pragma unroll
    for (int i = 0; i < 4; ++i) {
      f32x4 r = __builtin_amdgcn_mfma_f32_16x16x32_bf16(af[i], bfrag, zero, 0, 0, 0);
      r *= 2.5f;
      *reinterpret_cast<f32x4*>(&buf[cb][rlo][(((wv << 2) + i) << 4) + (kh << 2)]) = r;
    }
    __syncthreads();
  }
  // epilogue: drain chunk 7 from buf[1]
#pragma unroll
  for (int it = 0; it < 4; ++it) {
    const int row = (it << 2) + wv;
    const f32x4 v = *reinterpret_cast<const f32x4*>(&buf[1][row][lane << 2]);
    *reinterpret_cast<f32x4*>(obase + (size_t)row * NCOLS + 8 + (7 << 8) + (lane << 2)) = v;
  }
}

extern "C" void kernel_launch(void* const* d_in, const int* in_sizes, int n_in,
                              void* d_out, int out_size, void* d_ws, size_t ws_size,
                              hipStream_t stream) {
  const float* imq  = (const float*)d_in[0];
  const int*   salq = (const int*)d_in[1];
  const float* imk  = (const float*)d_in[2];
  const int*   salk = (const int*)d_in[3];
  const float* Wq   = (const float*)d_in[4];
  const float* Wbg  = (const float*)d_in[5];
  const float* Wk   = (const float*)d_in[6];
  const float* Wcls = (const float*)d_in[7];
  const float* objq = (const float*)d_in[8];
  float* out = (float*)d_out;
  char* ws = (char*)d_ws;

  int*    tileCnt  = (int*)(ws + WS_TILECNT);
  int*    tileBase = (int*)(ws + WS_TILEBASE);
  int*    nposp    = (int*)(ws + WS_NPOS);
  float*  lpln     = (float*)(ws + WS_LPLN);
  float*  wqt      = (float*)(ws + WS_WQT);
  float*  wkmt     = (float*)(ws + WS_WKMT);
  float*  psum     = (float*)(ws + WS_PSUM);
  float*  proto    = (float*)(ws + WS_PROTO);
  ushort* qt       = (ushort*)(ws + WS_QT);
  float*  clsel    = (float*)(ws + WS_CLSEL);
  int*    salsel   = (int*)(ws + WS_SALSEL);
  ushort* qsel     = (ushort*)(ws + WS_QSEL);

  hipLaunchKernelGGL(kP1, dim3(256), dim3(256), 0, stream, salq, tileCnt, Wq, Wk, wqt, wkmt, psum, lpln);
  hipLaunchKernelGGL(kP2, dim3(1), dim3(256), 0, stream, tileCnt, tileBase, nposp);
  hipLaunchKernelGGL(kAB, dim3(512), dim3(256), 0, stream, imq, imk, salq, salk, wqt, wkmt,
                     Wbg, Wcls, tileBase, qsel, clsel, salsel, lpln, psum);
  hipLaunchKernelGGL(kC, dim3(257), dim3(256), 0, stream, objq, psum, lpln, nposp, proto, qt,
                     out + OUT_NQ, out + OUT_LOSS);
  hipLaunchKernelGGL(kDE, dim3(4096), dim3(256), 0, stream, qsel, qt, proto, clsel, salsel,
                     out, (int*)(out + OUT_PL));
}

// Round 10
// 227.819 us; speedup vs baseline: 1.1321x; 1.1321x over previous
//
#include <hip/hip_runtime.h>

typedef __attribute__((ext_vector_type(8))) short short8;
typedef __attribute__((ext_vector_type(4))) float f32x4;
typedef __attribute__((ext_vector_type(2))) float f32x2;

constexpr int CIN  = 256;
constexpr int HWp  = 16384;        // H*W
constexpr int NSEL = 65536;
constexpr int NCOLS = 2056;

// out offsets (elements)
constexpr size_t OUT_PL   = (size_t)NSEL * NCOLS;  // pseudo_labels
constexpr size_t OUT_LOSS = OUT_PL + NSEL;         // sal_loss
constexpr size_t OUT_NQ   = OUT_LOSS + 1;          // new_queue

// ws offsets (bytes)
constexpr size_t WS_TILECNT  = 0;        // 256 int
constexpr size_t WS_TILEBASE = 2048;     // 256 int
constexpr size_t WS_NPOS     = 4096;     // int
constexpr size_t WS_LPLN     = 4104;     // 2 float
constexpr size_t WS_WQT      = 8192;     // 8192 f  (W_q transposed [256][32])
constexpr size_t WS_WKMT     = 40960;    // 8192 f  (momentum W_k transposed)
constexpr size_t WS_PSUM     = 73728;    // 256 f   (proto sums, atomically built)
constexpr size_t WS_PROTO    = 74752;    // 256 f   (normalized protos [8][32])
constexpr size_t WS_QT       = 131072;   // 65536 ushort (queue^T bf16 [2048][32])
constexpr size_t WS_CLSEL    = 262144;   // 65536 f
constexpr size_t WS_SALSEL   = 524288;   // 65536 int
constexpr size_t WS_QSEL     = 1048576;  // 65536*32 ushort (q_sel bf16)

static __device__ __forceinline__ unsigned short f2bf(float f) {
  const unsigned x = __float_as_uint(f);
  return (unsigned short)((x + 0x7fffu + ((x >> 16) & 1u)) >> 16);
}
static __device__ __forceinline__ float bf2f(unsigned short u) {
  return __uint_as_float(((unsigned)u) << 16);
}

// ---- P1: per-512-pixel-tile fg counts; blocks 0..31 also build transposed weights ----
__global__ __launch_bounds__(256) void kP1(const int* __restrict__ salq, int* __restrict__ tileCnt,
                                           const float* __restrict__ Wq, const float* __restrict__ Wk,
                                           float* __restrict__ wqt, float* __restrict__ wkmt,
                                           float* __restrict__ psum, float* __restrict__ lpln) {
  const int g = blockIdx.x, t = threadIdx.x;
  __shared__ int red[256];
  const int base = g << 9;
  red[t] = ((salq[base + 2 * t] != 0) ? 1 : 0) + ((salq[base + 2 * t + 1] != 0) ? 1 : 0);
  __syncthreads();
  for (int s = 128; s > 0; s >>= 1) { if (t < s) red[t] += red[t + s]; __syncthreads(); }
  if (t == 0) tileCnt[g] = red[0];
  if (g < 32) {
    const int idx = (g << 8) + t;
    const int o = idx & 31, c = idx >> 5;
    const float wq = Wq[o * 256 + c];
    wqt[idx] = wq;
    wkmt[idx] = 0.999f * Wk[o * 256 + c] + 0.001f * wq;
  }
  if (g == 32) { psum[t] = 0.f; if (t < 2) lpln[t] = 0.f; }
}

// ---- P2: exclusive scan of 256 tile counts ----
__global__ __launch_bounds__(256) void kP2(const int* __restrict__ tileCnt, int* __restrict__ tileBase,
                                           int* __restrict__ nposp) {
  const int t = threadIdx.x;
  __shared__ int sc[256];
  const int c0 = tileCnt[t];
  sc[t] = c0;
  __syncthreads();
  for (int off = 1; off < 256; off <<= 1) {
    int v = (t >= off) ? sc[t - off] : 0;
    __syncthreads();
    sc[t] += v;
    __syncthreads();
  }
  tileBase[t] = sc[t] - c0;
  if (t == 255) *nposp = sc[255];
}

// ---- AB: both conv passes, 2 px/thread. blocks 0..255: im_q; 256..511: im_k ----
__global__ __launch_bounds__(256) void kAB(
    const float* __restrict__ imq, const float* __restrict__ imk,
    const int* __restrict__ salq, const int* __restrict__ salk,
    const float* __restrict__ wqt, const float* __restrict__ wkmt,
    const float* __restrict__ wbg, const float* __restrict__ wcls,
    const int* __restrict__ tileBase,
    ushort* __restrict__ qsel, float* __restrict__ clsel, int* __restrict__ salsel,
    float* __restrict__ lpln, float* __restrict__ psum) {
  const int g = blockIdx.x, t = threadIdx.x;
  const bool isA = (g < 256);
  const int tile = isA ? g : (g - 256);
  const int base = tile << 9;            // 512 px per tile
  const int b = base >> 14;
  const int n = (base & (HWp - 1)) + (t << 1);
  const float* __restrict__ ip = (isA ? imq : imk) + (size_t)b * (CIN * HWp) + n;
  const float* __restrict__ wt0 = isA ? wqt : wkmt;

  float a0[32], a1[32];
#pragma unroll
  for (int o = 0; o < 32; ++o) { a0[o] = 0.f; a1[o] = 0.f; }
  float bg0 = 0.f, bg1 = 0.f;

#pragma unroll 8
  for (int c = 0; c < 256; ++c) {
    const f32x2 v = __builtin_nontemporal_load(
        reinterpret_cast<const f32x2*>(ip + (size_t)c * HWp));
    const float* wt = wt0 + (c << 5);
    const float wb = wbg[c];
#pragma unroll
    for (int o = 0; o < 32; ++o) {
      a0[o] = fmaf(wt[o], v.x, a0[o]);
      a1[o] = fmaf(wt[o], v.y, a1[o]);
    }
    bg0 = fmaf(wb, v.x, bg0);
    bg1 = fmaf(wb, v.y, bg1);
  }

  const int lane = t & 63, wv = t >> 6;
  const int flat0 = base + (t << 1);

  if (isA) {
    const int s0 = (salq[flat0] != 0) ? 1 : 0;
    const int s1 = (salq[flat0 + 1] != 0) ? 1 : 0;
    const unsigned spair = (unsigned)(s0 + s1);
    // block-wide exclusive prefix over thread fg-counts (flat order = pixel order)
    unsigned incl = spair;
#pragma unroll
    for (int off = 1; off < 64; off <<= 1) {
      unsigned u = __shfl_up(incl, off);
      if (lane >= off) incl += u;
    }
    __shared__ int wtot[4];
    if (lane == 63) wtot[wv] = (int)incl;
    __syncthreads();
    int wbase = 0;
    for (int i = 0; i < wv; ++i) wbase += wtot[i];
    const int excl = tileBase[tile] + wbase + (int)(incl - spair);

#pragma unroll
    for (int i = 0; i < 2; ++i) {
      const int si = i ? s1 : s0;
      const int rank = i ? (excl + s0) : excl;
      if (si && rank < NSEL) {
        float ss = 0.f;
#pragma unroll
        for (int o = 0; o < 32; ++o) { const float a = i ? a1[o] : a0[o]; ss = fmaf(a, a, ss); }
        const float inv = 1.f / fmaxf(sqrtf(ss), 1e-12f);
        float qn[32];
#pragma unroll
        for (int o = 0; o < 32; ++o) qn[o] = (i ? a1[o] : a0[o]) * inv;
        float m = -3.402823466e38f;
#pragma unroll
        for (int j = 0; j < 20; ++j) {
          float d = 0.f;
#pragma unroll
          for (int o = 0; o < 32; ++o) d = fmaf(wcls[(j << 5) + o], qn[o], d);
          m = fmaxf(m, d);
        }
        clsel[rank] = m;
        salsel[rank] = b;
        ushort* qp = qsel + ((size_t)rank << 5);
#pragma unroll
        for (int v4 = 0; v4 < 4; ++v4) {
          short8 v8;
#pragma unroll
          for (int j = 0; j < 8; ++j) v8[j] = (short)f2bf(qn[(v4 << 3) + j]);
          *reinterpret_cast<short8*>(qp + (v4 << 3)) = v8;
        }
      }
    }
    // balanced BCE partials
    const float gz0 = (bg0 >= 0.f) ? 1.f : 0.f;
    const float gz1 = (bg1 >= 0.f) ? 1.f : 0.f;
    const float lv0 = bg0 * ((float)s0 - gz0) - log1pf(expf(bg0 - 2.f * bg0 * gz0));
    const float lv1 = bg1 * ((float)s1 - gz1) - log1pf(expf(bg1 - 2.f * bg1 * gz1));
    float lp = -(s0 ? lv0 : 0.f) - (s1 ? lv1 : 0.f);
    float ln = -(s0 ? 0.f : lv0) - (s1 ? 0.f : lv1);
#pragma unroll
    for (int off = 32; off > 0; off >>= 1) { lp += __shfl_down(lp, off); ln += __shfl_down(ln, off); }
    __shared__ float slp[4], sln[4];
    if (lane == 0) { slp[wv] = lp; sln[wv] = ln; }
    __syncthreads();
    if (t == 0) {
      atomicAdd(&lpln[0], slp[0] + slp[1] + slp[2] + slp[3]);
      atomicAdd(&lpln[1], sln[0] + sln[1] + sln[2] + sln[3]);
    }
  } else {
    const int s0 = (salk[flat0] != 0) ? 1 : 0;
    const int s1 = (salk[flat0 + 1] != 0) ? 1 : 0;
    float ss0 = 0.f, ss1 = 0.f;
#pragma unroll
    for (int o = 0; o < 32; ++o) { ss0 = fmaf(a0[o], a0[o], ss0); ss1 = fmaf(a1[o], a1[o], ss1); }
    const float inv0 = s0 ? (1.f / fmaxf(sqrtf(ss0), 1e-12f)) : 0.f;
    const float inv1 = s1 ? (1.f / fmaxf(sqrtf(ss1), 1e-12f)) : 0.f;
    float p[32];
#pragma unroll
    for (int o = 0; o < 32; ++o) p[o] = a0[o] * inv0 + a1[o] * inv1;
#pragma unroll
    for (int o = 0; o < 32; ++o) {
#pragma unroll
      for (int off = 32; off > 0; off >>= 1) p[o] += __shfl_down(p[o], off);
    }
    __shared__ float sp[4][32];
    if (lane == 0) {
#pragma unroll
      for (int o = 0; o < 32; ++o) sp[wv][o] = p[o];
    }
    __syncthreads();
    if (t < 32) atomicAdd(&psum[(b << 5) + t], sp[0][t] + sp[1][t] + sp[2][t] + sp[3][t]);
  }
}

// ---- C: fused. Block 256: proto normalize + loss + new_queue head cols.
//      Blocks 0..255: bf16 queue transpose + new_queue tail copy. ----
__global__ __launch_bounds__(256) void kC(const float* __restrict__ objq, const float* __restrict__ psum,
                                          const float* __restrict__ lpln, const int* __restrict__ nposp,
                                          float* __restrict__ proto, ushort* __restrict__ qt,
                                          float* __restrict__ nq, float* __restrict__ outLoss) {
  const int g = blockIdx.x, t = threadIdx.x;
  if (g == 256) {
    __shared__ float sq[256];
    __shared__ float sinv[8];
    const float v = psum[t];
    sq[t] = v * v;
    __syncthreads();
    if (t < 8) {
      float s = 0.f;
      for (int o = 0; o < 32; ++o) s += sq[(t << 5) + o];
      sinv[t] = 1.f / fmaxf(sqrtf(s), 1e-12f);
    }
    __syncthreads();
    const float pv = v * sinv[t >> 5];
    proto[t] = pv;                           // t = p*32 + o
    const int p = t >> 5, o = t & 31;
    nq[(size_t)o * 2048 + p] = pv;           // new_queue head (first 8 cols)
    if (t == 0) {
      const float np = (float)(*nposp);
      outLoss[0] = ((131072.f - np) / 131072.f * lpln[0] + np / 131072.f * lpln[1]) / 131072.f;
    }
  } else {
    const int idx = (g << 8) + t;
    const int o = idx >> 11, j = idx & 2047;
    const float v = objq[idx];
    qt[(j << 5) + o] = f2bf(v);              // bank logits use the OLD queue
    if (j >= 8) nq[idx] = v;
  }
}

// ---- DE: logits. R8 structure (16 rows/block, 2 col phases, 2 blocks/CU,
// 4KB-contiguous row drains) + XCD-COMPACTING SWIZZLE: g' = (g&7)*512 + g>>3.
// Round-robin dispatch then gives each XCD a contiguous 512-group span, so its
// ~64 resident blocks write a ~17MB moving window (vs sampling all 539MB) ->
// dirty-line evictions leave L2 near-ordered, ~8 compact page streams device-
// wide instead of ~512. ----
__global__ __launch_bounds__(256) void kDE(const ushort* __restrict__ qsel, const ushort* __restrict__ qt,
                                           const float* __restrict__ proto, const float* __restrict__ clsel,
                                           const int* __restrict__ salsel,
                                           float* __restrict__ out, int* __restrict__ pl) {
  __shared__ float buf[16][1028];   // 16 rows x 1024 bank cols (+4 pad), 65.8 KB
  __shared__ float dd[16][9];
  __shared__ float hd[16][8];
  const int t = threadIdx.x;
  const int g = ((blockIdx.x & 7) << 9) + (blockIdx.x >> 3);   // XCD-compacting swizzle
  const int wv = t >> 6, lane = t & 63;
  const int r0 = g << 4;            // 16 rows per block
  if (t < 16) pl[r0 + t] = 0;

  const int rlo = lane & 15, kh = lane >> 4;
  const f32x4 zero = {0.f, 0.f, 0.f, 0.f};

  // B-fragment: the block's 16 q_sel rows (reused in both phases)
  const short8 bfrag = *reinterpret_cast<const short8*>(
      qsel + (size_t)(r0 + rlo) * 32 + kh * 8);
  const ushort* qa = qt + rlo * 32 + kh * 8;
  float* obase = out + (size_t)r0 * NCOLS;

  // head dots: 128 threads, row = t>>3, proto = t&7
  if (t < 128) {
    const int ri = t >> 3, pp = t & 7;
    const short8* qp = reinterpret_cast<const short8*>(qsel + ((size_t)(r0 + ri) << 5));
    float s = 0.f;
#pragma unroll
    for (int i = 0; i < 4; ++i) {
      const short8 v8 = qp[i];
#pragma unroll
      for (int j = 0; j < 8; ++j)
        s = fmaf(proto[(pp << 5) + (i << 3) + j], bf2f((unsigned short)v8[j]), s);
    }
    dd[ri][pp] = s;
  }
  __syncthreads();

  // ---- phase 0: head cols + bank tiles 0..63 ----
  if (t < 16) {
    const int b = salsel[r0 + t];
    hd[t][0] = clsel[r0 + t] * 2.5f;
#pragma unroll
    for (int c = 0; c < 7; ++c) {
      const int pi = c + ((c >= b) ? 1 : 0);
      hd[t][1 + c] = dd[t][pi] * 2.5f;
    }
  }
#pragma unroll 8
  for (int ct2 = 0; ct2 < 16; ++ct2) {
    const int lt = (wv << 4) + ct2;          // local tile 0..63
    const short8 afrag = *reinterpret_cast<const short8*>(qa + (size_t)lt * 512);
    f32x4 r = __builtin_amdgcn_mfma_f32_16x16x32_bf16(afrag, bfrag, zero, 0, 0, 0);
    r *= 2.5f;
    *reinterpret_cast<f32x4*>(&buf[rlo][(lt << 4) + (kh << 2)]) = r;
  }
  __syncthreads();
  // drain phase 0: head (cols 0..7) + rows x 4KB contiguous (cols 8..1031)
  if (t < 32) {
    const int rr = t >> 1, cc = (t & 1) << 2;
    *reinterpret_cast<f32x4*>(obase + (size_t)rr * NCOLS + cc) =
        *reinterpret_cast<const f32x4*>(&hd[rr][cc]);
  }
#pragma unroll
  for (int rr = 0; rr < 16; ++rr) {
    const f32x4 v = *reinterpret_cast<const f32x4*>(&buf[rr][t << 2]);
    *reinterpret_cast<f32x4*>(obase + (size_t)rr * NCOLS + 8 + (t << 2)) = v;
  }
  __syncthreads();

  // ---- phase 1: bank tiles 64..127 ----
#pragma unroll 8
  for (int ct2 = 0; ct2 < 16; ++ct2) {
    const int lt = (wv << 4) + ct2;          // local tile 0..63 -> global 64..127
    const short8 afrag = *reinterpret_cast<const short8*>(qa + (size_t)(lt + 64) * 512);
    f32x4 r = __builtin_amdgcn_mfma_f32_16x16x32_bf16(afrag, bfrag, zero, 0, 0, 0);
    r *= 2.5f;
    *reinterpret_cast<f32x4*>(&buf[rlo][(lt << 4) + (kh << 2)]) = r;
  }
  __syncthreads();
  // drain phase 1: rows x 4KB contiguous (cols 1032..2055)
#pragma unroll
  for (int rr = 0; rr < 16; ++rr) {
    const f32x4 v = *reinterpret_cast<const f32x4*>(&buf[rr][t << 2]);
    *reinterpret_cast<f32x4*>(obase + (size_t)rr * NCOLS + 1032 + (t << 2)) = v;
  }
}

extern "C" void kernel_launch(void* const* d_in, const int* in_sizes, int n_in,
                              void* d_out, int out_size, void* d_ws, size_t ws_size,
                              hipStream_t stream) {
  const float* imq  = (const float*)d_in[0];
  const int*   salq = (const int*)d_in[1];
  const float* imk  = (const float*)d_in[2];
  const int*   salk = (const int*)d_in[3];
  const float* Wq   = (const float*)d_in[4];
  const float* Wbg  = (const float*)d_in[5];
  const float* Wk   = (const float*)d_in[6];
  const float* Wcls = (const float*)d_in[7];
  const float* objq = (const float*)d_in[8];
  float* out = (float*)d_out;
  char* ws = (char*)d_ws;

  int*    tileCnt  = (int*)(ws + WS_TILECNT);
  int*    tileBase = (int*)(ws + WS_TILEBASE);
  int*    nposp    = (int*)(ws + WS_NPOS);
  float*  lpln     = (float*)(ws + WS_LPLN);
  float*  wqt      = (float*)(ws + WS_WQT);
  float*  wkmt     = (float*)(ws + WS_WKMT);
  float*  psum     = (float*)(ws + WS_PSUM);
  float*  proto    = (float*)(ws + WS_PROTO);
  ushort* qt       = (ushort*)(ws + WS_QT);
  float*  clsel    = (float*)(ws + WS_CLSEL);
  int*    salsel   = (int*)(ws + WS_SALSEL);
  ushort* qsel     = (ushort*)(ws + WS_QSEL);

  hipLaunchKernelGGL(kP1, dim3(256), dim3(256), 0, stream, salq, tileCnt, Wq, Wk, wqt, wkmt, psum, lpln);
  hipLaunchKernelGGL(kP2, dim3(1), dim3(256), 0, stream, tileCnt, tileBase, nposp);
  hipLaunchKernelGGL(kAB, dim3(512), dim3(256), 0, stream, imq, imk, salq, salk, wqt, wkmt,
                     Wbg, Wcls, tileBase, qsel, clsel, salsel, lpln, psum);
  hipLaunchKernelGGL(kC, dim3(257), dim3(256), 0, stream, objq, psum, lpln, nposp, proto, qt,
                     out + OUT_NQ, out + OUT_LOSS);
  hipLaunchKernelGGL(kDE, dim3(4096), dim3(256), 0, stream, qsel, qt, proto, clsel, salsel,
                     out, (int*)(out + OUT_PL));
}

// Round 11
// 214.135 us; speedup vs baseline: 1.2045x; 1.0639x over previous
//
#include <hip/hip_runtime.h>

typedef __attribute__((ext_vector_type(8))) short short8;
typedef __attribute__((ext_vector_type(4))) float f32x4;
typedef __attribute__((ext_vector_type(2))) float f32x2;

constexpr int CIN  = 256;
constexpr int HWp  = 16384;        // H*W
constexpr int NSEL = 65536;
constexpr int NCOLS = 2056;

// out offsets (elements)
constexpr size_t OUT_PL   = (size_t)NSEL * NCOLS;  // pseudo_labels
constexpr size_t OUT_LOSS = OUT_PL + NSEL;         // sal_loss
constexpr size_t OUT_NQ   = OUT_LOSS + 1;          // new_queue

// ws offsets (bytes)
constexpr size_t WS_TILECNT  = 0;        // 256 int
constexpr size_t WS_TILEBASE = 2048;     // 256 int
constexpr size_t WS_NPOS     = 4096;     // int
constexpr size_t WS_LPLN     = 4104;     // 2 float
constexpr size_t WS_WQT      = 8192;     // 8192 f  (W_q transposed [256][32])
constexpr size_t WS_WKMT     = 40960;    // 8192 f  (momentum W_k transposed)
constexpr size_t WS_PSUM     = 73728;    // 256 f   (proto sums, atomically built)
constexpr size_t WS_PROTO    = 74752;    // 256 f   (normalized protos [8][32])
constexpr size_t WS_QT       = 131072;   // 65536 ushort (queue^T bf16 [2048][32])
constexpr size_t WS_CLSEL    = 262144;   // 65536 f
constexpr size_t WS_SALSEL   = 524288;   // 65536 int
constexpr size_t WS_QSEL     = 1048576;  // 65536*32 ushort (q_sel bf16)

static __device__ __forceinline__ unsigned short f2bf(float f) {
  const unsigned x = __float_as_uint(f);
  return (unsigned short)((x + 0x7fffu + ((x >> 16) & 1u)) >> 16);
}
static __device__ __forceinline__ float bf2f(unsigned short u) {
  return __uint_as_float(((unsigned)u) << 16);
}

// ---- P1: per-512-pixel-tile fg counts; blocks 0..31 also build transposed weights ----
__global__ __launch_bounds__(256) void kP1(const int* __restrict__ salq, int* __restrict__ tileCnt,
                                           const float* __restrict__ Wq, const float* __restrict__ Wk,
                                           float* __restrict__ wqt, float* __restrict__ wkmt,
                                           float* __restrict__ psum, float* __restrict__ lpln) {
  const int g = blockIdx.x, t = threadIdx.x;
  __shared__ int red[256];
  const int base = g << 9;
  red[t] = ((salq[base + 2 * t] != 0) ? 1 : 0) + ((salq[base + 2 * t + 1] != 0) ? 1 : 0);
  __syncthreads();
  for (int s = 128; s > 0; s >>= 1) { if (t < s) red[t] += red[t + s]; __syncthreads(); }
  if (t == 0) tileCnt[g] = red[0];
  if (g < 32) {
    const int idx = (g << 8) + t;
    const int o = idx & 31, c = idx >> 5;
    const float wq = Wq[o * 256 + c];
    wqt[idx] = wq;
    wkmt[idx] = 0.999f * Wk[o * 256 + c] + 0.001f * wq;
  }
  if (g == 32) { psum[t] = 0.f; if (t < 2) lpln[t] = 0.f; }
}

// ---- P2: exclusive scan of 256 tile counts ----
__global__ __launch_bounds__(256) void kP2(const int* __restrict__ tileCnt, int* __restrict__ tileBase,
                                           int* __restrict__ nposp) {
  const int t = threadIdx.x;
  __shared__ int sc[256];
  const int c0 = tileCnt[t];
  sc[t] = c0;
  __syncthreads();
  for (int off = 1; off < 256; off <<= 1) {
    int v = (t >= off) ? sc[t - off] : 0;
    __syncthreads();
    sc[t] += v;
    __syncthreads();
  }
  tileBase[t] = sc[t] - c0;
  if (t == 255) *nposp = sc[255];
}

// ---- AB: both conv passes, 2 px/thread. blocks 0..255: im_q; 256..511: im_k ----
__global__ __launch_bounds__(256) void kAB(
    const float* __restrict__ imq, const float* __restrict__ imk,
    const int* __restrict__ salq, const int* __restrict__ salk,
    const float* __restrict__ wqt, const float* __restrict__ wkmt,
    const float* __restrict__ wbg, const float* __restrict__ wcls,
    const int* __restrict__ tileBase,
    ushort* __restrict__ qsel, float* __restrict__ clsel, int* __restrict__ salsel,
    float* __restrict__ lpln, float* __restrict__ psum) {
  const int g = blockIdx.x, t = threadIdx.x;
  const bool isA = (g < 256);
  const int tile = isA ? g : (g - 256);
  const int base = tile << 9;            // 512 px per tile
  const int b = base >> 14;
  const int n = (base & (HWp - 1)) + (t << 1);
  const float* __restrict__ ip = (isA ? imq : imk) + (size_t)b * (CIN * HWp) + n;
  const float* __restrict__ wt0 = isA ? wqt : wkmt;

  float a0[32], a1[32];
#pragma unroll
  for (int o = 0; o < 32; ++o) { a0[o] = 0.f; a1[o] = 0.f; }
  float bg0 = 0.f, bg1 = 0.f;

#pragma unroll 8
  for (int c = 0; c < 256; ++c) {
    const f32x2 v = __builtin_nontemporal_load(
        reinterpret_cast<const f32x2*>(ip + (size_t)c * HWp));
    const float* wt = wt0 + (c << 5);
    const float wb = wbg[c];
#pragma unroll
    for (int o = 0; o < 32; ++o) {
      a0[o] = fmaf(wt[o], v.x, a0[o]);
      a1[o] = fmaf(wt[o], v.y, a1[o]);
    }
    bg0 = fmaf(wb, v.x, bg0);
    bg1 = fmaf(wb, v.y, bg1);
  }

  const int lane = t & 63, wv = t >> 6;
  const int flat0 = base + (t << 1);

  if (isA) {
    const int s0 = (salq[flat0] != 0) ? 1 : 0;
    const int s1 = (salq[flat0 + 1] != 0) ? 1 : 0;
    const unsigned spair = (unsigned)(s0 + s1);
    // block-wide exclusive prefix over thread fg-counts (flat order = pixel order)
    unsigned incl = spair;
#pragma unroll
    for (int off = 1; off < 64; off <<= 1) {
      unsigned u = __shfl_up(incl, off);
      if (lane >= off) incl += u;
    }
    __shared__ int wtot[4];
    if (lane == 63) wtot[wv] = (int)incl;
    __syncthreads();
    int wbase = 0;
    for (int i = 0; i < wv; ++i) wbase += wtot[i];
    const int excl = tileBase[tile] + wbase + (int)(incl - spair);

#pragma unroll
    for (int i = 0; i < 2; ++i) {
      const int si = i ? s1 : s0;
      const int rank = i ? (excl + s0) : excl;
      if (si && rank < NSEL) {
        float ss = 0.f;
#pragma unroll
        for (int o = 0; o < 32; ++o) { const float a = i ? a1[o] : a0[o]; ss = fmaf(a, a, ss); }
        const float inv = 1.f / fmaxf(sqrtf(ss), 1e-12f);
        float qn[32];
#pragma unroll
        for (int o = 0; o < 32; ++o) qn[o] = (i ? a1[o] : a0[o]) * inv;
        float m = -3.402823466e38f;
#pragma unroll
        for (int j = 0; j < 20; ++j) {
          float d = 0.f;
#pragma unroll
          for (int o = 0; o < 32; ++o) d = fmaf(wcls[(j << 5) + o], qn[o], d);
          m = fmaxf(m, d);
        }
        clsel[rank] = m;
        salsel[rank] = b;
        ushort* qp = qsel + ((size_t)rank << 5);
#pragma unroll
        for (int v4 = 0; v4 < 4; ++v4) {
          short8 v8;
#pragma unroll
          for (int j = 0; j < 8; ++j) v8[j] = (short)f2bf(qn[(v4 << 3) + j]);
          *reinterpret_cast<short8*>(qp + (v4 << 3)) = v8;
        }
      }
    }
    // balanced BCE partials
    const float gz0 = (bg0 >= 0.f) ? 1.f : 0.f;
    const float gz1 = (bg1 >= 0.f) ? 1.f : 0.f;
    const float lv0 = bg0 * ((float)s0 - gz0) - log1pf(expf(bg0 - 2.f * bg0 * gz0));
    const float lv1 = bg1 * ((float)s1 - gz1) - log1pf(expf(bg1 - 2.f * bg1 * gz1));
    float lp = -(s0 ? lv0 : 0.f) - (s1 ? lv1 : 0.f);
    float ln = -(s0 ? 0.f : lv0) - (s1 ? 0.f : lv1);
#pragma unroll
    for (int off = 32; off > 0; off >>= 1) { lp += __shfl_down(lp, off); ln += __shfl_down(ln, off); }
    __shared__ float slp[4], sln[4];
    if (lane == 0) { slp[wv] = lp; sln[wv] = ln; }
    __syncthreads();
    if (t == 0) {
      atomicAdd(&lpln[0], slp[0] + slp[1] + slp[2] + slp[3]);
      atomicAdd(&lpln[1], sln[0] + sln[1] + sln[2] + sln[3]);
    }
  } else {
    const int s0 = (salk[flat0] != 0) ? 1 : 0;
    const int s1 = (salk[flat0 + 1] != 0) ? 1 : 0;
    float ss0 = 0.f, ss1 = 0.f;
#pragma unroll
    for (int o = 0; o < 32; ++o) { ss0 = fmaf(a0[o], a0[o], ss0); ss1 = fmaf(a1[o], a1[o], ss1); }
    const float inv0 = s0 ? (1.f / fmaxf(sqrtf(ss0), 1e-12f)) : 0.f;
    const float inv1 = s1 ? (1.f / fmaxf(sqrtf(ss1), 1e-12f)) : 0.f;
    float p[32];
#pragma unroll
    for (int o = 0; o < 32; ++o) p[o] = a0[o] * inv0 + a1[o] * inv1;
#pragma unroll
    for (int o = 0; o < 32; ++o) {
#pragma unroll
      for (int off = 32; off > 0; off >>= 1) p[o] += __shfl_down(p[o], off);
    }
    __shared__ float sp[4][32];
    if (lane == 0) {
#pragma unroll
      for (int o = 0; o < 32; ++o) sp[wv][o] = p[o];
    }
    __syncthreads();
    if (t < 32) atomicAdd(&psum[(b << 5) + t], sp[0][t] + sp[1][t] + sp[2][t] + sp[3][t]);
  }
}

// ---- C: fused. Block 256: proto normalize + loss + new_queue head cols.
//      Blocks 0..255: bf16 queue transpose + new_queue tail copy. ----
__global__ __launch_bounds__(256) void kC(const float* __restrict__ objq, const float* __restrict__ psum,
                                          const float* __restrict__ lpln, const int* __restrict__ nposp,
                                          float* __restrict__ proto, ushort* __restrict__ qt,
                                          float* __restrict__ nq, float* __restrict__ outLoss) {
  const int g = blockIdx.x, t = threadIdx.x;
  if (g == 256) {
    __shared__ float sq[256];
    __shared__ float sinv[8];
    const float v = psum[t];
    sq[t] = v * v;
    __syncthreads();
    if (t < 8) {
      float s = 0.f;
      for (int o = 0; o < 32; ++o) s += sq[(t << 5) + o];
      sinv[t] = 1.f / fmaxf(sqrtf(s), 1e-12f);
    }
    __syncthreads();
    const float pv = v * sinv[t >> 5];
    proto[t] = pv;                           // t = p*32 + o
    const int p = t >> 5, o = t & 31;
    nq[(size_t)o * 2048 + p] = pv;           // new_queue head (first 8 cols)
    if (t == 0) {
      const float np = (float)(*nposp);
      outLoss[0] = ((131072.f - np) / 131072.f * lpln[0] + np / 131072.f * lpln[1]) / 131072.f;
    }
  } else {
    const int idx = (g << 8) + t;
    const int o = idx >> 11, j = idx & 2047;
    const float v = objq[idx];
    qt[(j << 5) + o] = f2bf(v);              // bank logits use the OLD queue
    if (j >= 8) nq[idx] = v;
  }
}

// ---- DE: logits. R10 structure (16 rows/block, 2 col phases, 2 blocks/CU,
// XCD-compacting swizzle, 4KB-contiguous row drains) + NONTEMPORAL stores:
// nt (evict-first/streaming) makes stores reach HBM near issue order instead
// of LRU-eviction order, preserving the compact per-XCD page stream. Head
// cols merged into the phase-0 buffer so each row's first drain sweep starts
// line-aligned at col 0 (64 complete lines per instruction stream). ----
__global__ __launch_bounds__(256) void kDE(const ushort* __restrict__ qsel, const ushort* __restrict__ qt,
                                           const float* __restrict__ proto, const float* __restrict__ clsel,
                                           const int* __restrict__ salsel,
                                           float* __restrict__ out, int* __restrict__ pl) {
  __shared__ float buf[16][1036];   // phase0: cols 0..1031 (head 0..7 + tiles); phase1: cols 0..1023
  __shared__ float dd[16][9];
  const int t = threadIdx.x;
  const int g = ((blockIdx.x & 7) << 9) + (blockIdx.x >> 3);   // XCD-compacting swizzle
  const int wv = t >> 6, lane = t & 63;
  const int r0 = g << 4;            // 16 rows per block
  if (t < 16) pl[r0 + t] = 0;

  const int rlo = lane & 15, kh = lane >> 4;
  const f32x4 zero = {0.f, 0.f, 0.f, 0.f};

  // B-fragment: the block's 16 q_sel rows (reused in both phases)
  const short8 bfrag = *reinterpret_cast<const short8*>(
      qsel + (size_t)(r0 + rlo) * 32 + kh * 8);
  const ushort* qa = qt + rlo * 32 + kh * 8;
  float* obase = out + (size_t)r0 * NCOLS;

  // head dots: 128 threads, row = t>>3, proto = t&7
  if (t < 128) {
    const int ri = t >> 3, pp = t & 7;
    const short8* qp = reinterpret_cast<const short8*>(qsel + ((size_t)(r0 + ri) << 5));
    float s = 0.f;
#pragma unroll
    for (int i = 0; i < 4; ++i) {
      const short8 v8 = qp[i];
#pragma unroll
      for (int j = 0; j < 8; ++j)
        s = fmaf(proto[(pp << 5) + (i << 3) + j], bf2f((unsigned short)v8[j]), s);
    }
    dd[ri][pp] = s;
  }
  __syncthreads();

  // ---- phase 0: head cols (buf 0..7) + bank tiles 0..63 (buf 8..1031) ----
  if (t < 16) {
    const int b = salsel[r0 + t];
    buf[t][0] = clsel[r0 + t] * 2.5f;
#pragma unroll
    for (int c = 0; c < 7; ++c) {
      const int pi = c + ((c >= b) ? 1 : 0);
      buf[t][1 + c] = dd[t][pi] * 2.5f;
    }
  }
#pragma unroll 8
  for (int ct2 = 0; ct2 < 16; ++ct2) {
    const int lt = (wv << 4) + ct2;          // local tile 0..63
    const short8 afrag = *reinterpret_cast<const short8*>(qa + (size_t)lt * 512);
    f32x4 r = __builtin_amdgcn_mfma_f32_16x16x32_bf16(afrag, bfrag, zero, 0, 0, 0);
    r *= 2.5f;
    *reinterpret_cast<f32x4*>(&buf[rlo][8 + (lt << 4) + (kh << 2)]) = r;
  }
  __syncthreads();
  // drain phase 0: per row, bytes 0..4096 (64 complete lines) + 32B tail
#pragma unroll
  for (int rr = 0; rr < 16; ++rr) {
    const f32x4 v = *reinterpret_cast<const f32x4*>(&buf[rr][t << 2]);
    __builtin_nontemporal_store(v, reinterpret_cast<f32x4*>(obase + (size_t)rr * NCOLS + (t << 2)));
  }
  if (t < 32) {
    const int rr = t >> 1, u = t & 1;
    const f32x4 v = *reinterpret_cast<const f32x4*>(&buf[rr][1024 + (u << 2)]);
    __builtin_nontemporal_store(v, reinterpret_cast<f32x4*>(obase + (size_t)rr * NCOLS + 1024 + (u << 2)));
  }
  __syncthreads();

  // ---- phase 1: bank tiles 64..127 (buf cols 0..1023) ----
#pragma unroll 8
  for (int ct2 = 0; ct2 < 16; ++ct2) {
    const int lt = (wv << 4) + ct2;          // local tile 0..63 -> global 64..127
    const short8 afrag = *reinterpret_cast<const short8*>(qa + (size_t)(lt + 64) * 512);
    f32x4 r = __builtin_amdgcn_mfma_f32_16x16x32_bf16(afrag, bfrag, zero, 0, 0, 0);
    r *= 2.5f;
    *reinterpret_cast<f32x4*>(&buf[rlo][(lt << 4) + (kh << 2)]) = r;
  }
  __syncthreads();
  // drain phase 1: rows x 4KB contiguous (cols 1032..2055)
#pragma unroll
  for (int rr = 0; rr < 16; ++rr) {
    const f32x4 v = *reinterpret_cast<const f32x4*>(&buf[rr][t << 2]);
    __builtin_nontemporal_store(v, reinterpret_cast<f32x4*>(obase + (size_t)rr * NCOLS + 1032 + (t << 2)));
  }
}

extern "C" void kernel_launch(void* const* d_in, const int* in_sizes, int n_in,
                              void* d_out, int out_size, void* d_ws, size_t ws_size,
                              hipStream_t stream) {
  const float* imq  = (const float*)d_in[0];
  const int*   salq = (const int*)d_in[1];
  const float* imk  = (const float*)d_in[2];
  const int*   salk = (const int*)d_in[3];
  const float* Wq   = (const float*)d_in[4];
  const float* Wbg  = (const float*)d_in[5];
  const float* Wk   = (const float*)d_in[6];
  const float* Wcls = (const float*)d_in[7];
  const float* objq = (const float*)d_in[8];
  float* out = (float*)d_out;
  char* ws = (char*)d_ws;

  int*    tileCnt  = (int*)(ws + WS_TILECNT);
  int*    tileBase = (int*)(ws + WS_TILEBASE);
  int*    nposp    = (int*)(ws + WS_NPOS);
  float*  lpln     = (float*)(ws + WS_LPLN);
  float*  wqt      = (float*)(ws + WS_WQT);
  float*  wkmt     = (float*)(ws + WS_WKMT);
  float*  psum     = (float*)(ws + WS_PSUM);
  float*  proto    = (float*)(ws + WS_PROTO);
  ushort* qt       = (ushort*)(ws + WS_QT);
  float*  clsel    = (float*)(ws + WS_CLSEL);
  int*    salsel   = (int*)(ws + WS_SALSEL);
  ushort* qsel     = (ushort*)(ws + WS_QSEL);

  hipLaunchKernelGGL(kP1, dim3(256), dim3(256), 0, stream, salq, tileCnt, Wq, Wk, wqt, wkmt, psum, lpln);
  hipLaunchKernelGGL(kP2, dim3(1), dim3(256), 0, stream, tileCnt, tileBase, nposp);
  hipLaunchKernelGGL(kAB, dim3(512), dim3(256), 0, stream, imq, imk, salq, salk, wqt, wkmt,
                     Wbg, Wcls, tileBase, qsel, clsel, salsel, lpln, psum);
  hipLaunchKernelGGL(kC, dim3(257), dim3(256), 0, stream, objq, psum, lpln, nposp, proto, qt,
                     out + OUT_NQ, out + OUT_LOSS);
  hipLaunchKernelGGL(kDE, dim3(4096), dim3(256), 0, stream, qsel, qt, proto, clsel, salsel,
                     out, (int*)(out + OUT_PL));
}

// Round 12
// 203.422 us; speedup vs baseline: 1.2679x; 1.0527x over previous
//
#include <hip/hip_runtime.h>

typedef __attribute__((ext_vector_type(8))) short short8;
typedef __attribute__((ext_vector_type(4))) float f32x4;
typedef __attribute__((ext_vector_type(2))) float f32x2;

constexpr int CIN  = 256;
constexpr int HWp  = 16384;        // H*W
constexpr int NSEL = 65536;
constexpr int NCOLS = 2056;

// out offsets (elements)
constexpr size_t OUT_PL   = (size_t)NSEL * NCOLS;  // pseudo_labels
constexpr size_t OUT_LOSS = OUT_PL + NSEL;         // sal_loss
constexpr size_t OUT_NQ   = OUT_LOSS + 1;          // new_queue

// ws offsets (bytes)
constexpr size_t WS_TILECNT  = 0;        // 256 int
constexpr size_t WS_TILEBASE = 2048;     // 256 int
constexpr size_t WS_NPOS     = 4096;     // int
constexpr size_t WS_LPLN     = 4104;     // 2 float
constexpr size_t WS_WQT      = 8192;     // 8192 f  (W_q transposed [256][32])
constexpr size_t WS_WKMT     = 40960;    // 8192 f  (momentum W_k transposed)
constexpr size_t WS_PSUM     = 73728;    // 256 f   (proto sums, atomically built)
constexpr size_t WS_PROTO    = 74752;    // 256 f   (normalized protos [8][32])
constexpr size_t WS_QT       = 131072;   // 65536 ushort (queue^T bf16 [2048][32])
constexpr size_t WS_CLSEL    = 262144;   // 65536 f
constexpr size_t WS_SALSEL   = 524288;   // 65536 int
constexpr size_t WS_QSEL     = 1048576;  // 65536*32 ushort (q_sel bf16)

static __device__ __forceinline__ unsigned short f2bf(float f) {
  const unsigned x = __float_as_uint(f);
  return (unsigned short)((x + 0x7fffu + ((x >> 16) & 1u)) >> 16);
}
static __device__ __forceinline__ float bf2f(unsigned short u) {
  return __uint_as_float(((unsigned)u) << 16);
}

// ---- P1: per-512-pixel-tile fg counts; blocks 0..31 also build transposed weights ----
__global__ __launch_bounds__(256) void kP1(const int* __restrict__ salq, int* __restrict__ tileCnt,
                                           const float* __restrict__ Wq, const float* __restrict__ Wk,
                                           float* __restrict__ wqt, float* __restrict__ wkmt,
                                           float* __restrict__ psum, float* __restrict__ lpln) {
  const int g = blockIdx.x, t = threadIdx.x;
  __shared__ int red[256];
  const int base = g << 9;
  red[t] = ((salq[base + 2 * t] != 0) ? 1 : 0) + ((salq[base + 2 * t + 1] != 0) ? 1 : 0);
  __syncthreads();
  for (int s = 128; s > 0; s >>= 1) { if (t < s) red[t] += red[t + s]; __syncthreads(); }
  if (t == 0) tileCnt[g] = red[0];
  if (g < 32) {
    const int idx = (g << 8) + t;
    const int o = idx & 31, c = idx >> 5;
    const float wq = Wq[o * 256 + c];
    wqt[idx] = wq;
    wkmt[idx] = 0.999f * Wk[o * 256 + c] + 0.001f * wq;
  }
  if (g == 32) { psum[t] = 0.f; if (t < 2) lpln[t] = 0.f; }
}

// ---- P2: exclusive scan of 256 tile counts ----
__global__ __launch_bounds__(256) void kP2(const int* __restrict__ tileCnt, int* __restrict__ tileBase,
                                           int* __restrict__ nposp) {
  const int t = threadIdx.x;
  __shared__ int sc[256];
  const int c0 = tileCnt[t];
  sc[t] = c0;
  __syncthreads();
  for (int off = 1; off < 256; off <<= 1) {
    int v = (t >= off) ? sc[t - off] : 0;
    __syncthreads();
    sc[t] += v;
    __syncthreads();
  }
  tileBase[t] = sc[t] - c0;
  if (t == 255) *nposp = sc[255];
}

// ---- AB: both conv passes, 2 px/thread. XCD-compacting swizzle so each XCD
// reads a contiguous ~33MB image window (same mechanism as kDE's write win).
__global__ __launch_bounds__(256) void kAB(
    const float* __restrict__ imq, const float* __restrict__ imk,
    const int* __restrict__ salq, const int* __restrict__ salk,
    const float* __restrict__ wqt, const float* __restrict__ wkmt,
    const float* __restrict__ wbg, const float* __restrict__ wcls,
    const int* __restrict__ tileBase,
    ushort* __restrict__ qsel, float* __restrict__ clsel, int* __restrict__ salsel,
    float* __restrict__ lpln, float* __restrict__ psum) {
  const int g = ((blockIdx.x & 7) << 6) + (blockIdx.x >> 3);   // XCD-compacting swizzle
  const int t = threadIdx.x;
  const bool isA = (g < 256);
  const int tile = isA ? g : (g - 256);
  const int base = tile << 9;            // 512 px per tile
  const int b = base >> 14;
  const int n = (base & (HWp - 1)) + (t << 1);
  const float* __restrict__ ip = (isA ? imq : imk) + (size_t)b * (CIN * HWp) + n;
  const float* __restrict__ wt0 = isA ? wqt : wkmt;

  float a0[32], a1[32];
#pragma unroll
  for (int o = 0; o < 32; ++o) { a0[o] = 0.f; a1[o] = 0.f; }
  float bg0 = 0.f, bg1 = 0.f;

#pragma unroll 8
  for (int c = 0; c < 256; ++c) {
    const f32x2 v = __builtin_nontemporal_load(
        reinterpret_cast<const f32x2*>(ip + (size_t)c * HWp));
    const float* wt = wt0 + (c << 5);
    const float wb = wbg[c];
#pragma unroll
    for (int o = 0; o < 32; ++o) {
      a0[o] = fmaf(wt[o], v.x, a0[o]);
      a1[o] = fmaf(wt[o], v.y, a1[o]);
    }
    bg0 = fmaf(wb, v.x, bg0);
    bg1 = fmaf(wb, v.y, bg1);
  }

  const int lane = t & 63, wv = t >> 6;
  const int flat0 = base + (t << 1);

  if (isA) {
    const int s0 = (salq[flat0] != 0) ? 1 : 0;
    const int s1 = (salq[flat0 + 1] != 0) ? 1 : 0;
    const unsigned spair = (unsigned)(s0 + s1);
    // block-wide exclusive prefix over thread fg-counts (flat order = pixel order)
    unsigned incl = spair;
#pragma unroll
    for (int off = 1; off < 64; off <<= 1) {
      unsigned u = __shfl_up(incl, off);
      if (lane >= off) incl += u;
    }
    __shared__ int wtot[4];
    if (lane == 63) wtot[wv] = (int)incl;
    __syncthreads();
    int wbase = 0;
    for (int i = 0; i < wv; ++i) wbase += wtot[i];
    const int excl = tileBase[tile] + wbase + (int)(incl - spair);

#pragma unroll
    for (int i = 0; i < 2; ++i) {
      const int si = i ? s1 : s0;
      const int rank = i ? (excl + s0) : excl;
      if (si && rank < NSEL) {
        float ss = 0.f;
#pragma unroll
        for (int o = 0; o < 32; ++o) { const float a = i ? a1[o] : a0[o]; ss = fmaf(a, a, ss); }
        const float inv = 1.f / fmaxf(sqrtf(ss), 1e-12f);
        float qn[32];
#pragma unroll
        for (int o = 0; o < 32; ++o) qn[o] = (i ? a1[o] : a0[o]) * inv;
        float m = -3.402823466e38f;
#pragma unroll
        for (int j = 0; j < 20; ++j) {
          float d = 0.f;
#pragma unroll
          for (int o = 0; o < 32; ++o) d = fmaf(wcls[(j << 5) + o], qn[o], d);
          m = fmaxf(m, d);
        }
        clsel[rank] = m;
        salsel[rank] = b;
        ushort* qp = qsel + ((size_t)rank << 5);
#pragma unroll
        for (int v4 = 0; v4 < 4; ++v4) {
          short8 v8;
#pragma unroll
          for (int j = 0; j < 8; ++j) v8[j] = (short)f2bf(qn[(v4 << 3) + j]);
          *reinterpret_cast<short8*>(qp + (v4 << 3)) = v8;
        }
      }
    }
    // balanced BCE partials
    const float gz0 = (bg0 >= 0.f) ? 1.f : 0.f;
    const float gz1 = (bg1 >= 0.f) ? 1.f : 0.f;
    const float lv0 = bg0 * ((float)s0 - gz0) - log1pf(expf(bg0 - 2.f * bg0 * gz0));
    const float lv1 = bg1 * ((float)s1 - gz1) - log1pf(expf(bg1 - 2.f * bg1 * gz1));
    float lp = -(s0 ? lv0 : 0.f) - (s1 ? lv1 : 0.f);
    float ln = -(s0 ? 0.f : lv0) - (s1 ? 0.f : lv1);
#pragma unroll
    for (int off = 32; off > 0; off >>= 1) { lp += __shfl_down(lp, off); ln += __shfl_down(ln, off); }
    __shared__ float slp[4], sln[4];
    if (lane == 0) { slp[wv] = lp; sln[wv] = ln; }
    __syncthreads();
    if (t == 0) {
      atomicAdd(&lpln[0], slp[0] + slp[1] + slp[2] + slp[3]);
      atomicAdd(&lpln[1], sln[0] + sln[1] + sln[2] + sln[3]);
    }
  } else {
    const int s0 = (salk[flat0] != 0) ? 1 : 0;
    const int s1 = (salk[flat0 + 1] != 0) ? 1 : 0;
    float ss0 = 0.f, ss1 = 0.f;
#pragma unroll
    for (int o = 0; o < 32; ++o) { ss0 = fmaf(a0[o], a0[o], ss0); ss1 = fmaf(a1[o], a1[o], ss1); }
    const float inv0 = s0 ? (1.f / fmaxf(sqrtf(ss0), 1e-12f)) : 0.f;
    const float inv1 = s1 ? (1.f / fmaxf(sqrtf(ss1), 1e-12f)) : 0.f;
    float p[32];
#pragma unroll
    for (int o = 0; o < 32; ++o) p[o] = a0[o] * inv0 + a1[o] * inv1;
#pragma unroll
    for (int o = 0; o < 32; ++o) {
#pragma unroll
      for (int off = 32; off > 0; off >>= 1) p[o] += __shfl_down(p[o], off);
    }
    __shared__ float sp[4][32];
    if (lane == 0) {
#pragma unroll
      for (int o = 0; o < 32; ++o) sp[wv][o] = p[o];
    }
    __syncthreads();
    if (t < 32) atomicAdd(&psum[(b << 5) + t], sp[0][t] + sp[1][t] + sp[2][t] + sp[3][t]);
  }
}

// ---- C: fused. Block 256: proto normalize + loss + new_queue head cols.
//      Blocks 0..255: bf16 queue transpose + new_queue tail copy. ----
__global__ __launch_bounds__(256) void kC(const float* __restrict__ objq, const float* __restrict__ psum,
                                          const float* __restrict__ lpln, const int* __restrict__ nposp,
                                          float* __restrict__ proto, ushort* __restrict__ qt,
                                          float* __restrict__ nq, float* __restrict__ outLoss) {
  const int g = blockIdx.x, t = threadIdx.x;
  if (g == 256) {
    __shared__ float sq[256];
    __shared__ float sinv[8];
    const float v = psum[t];
    sq[t] = v * v;
    __syncthreads();
    if (t < 8) {
      float s = 0.f;
      for (int o = 0; o < 32; ++o) s += sq[(t << 5) + o];
      sinv[t] = 1.f / fmaxf(sqrtf(s), 1e-12f);
    }
    __syncthreads();
    const float pv = v * sinv[t >> 5];
    proto[t] = pv;                           // t = p*32 + o
    const int p = t >> 5, o = t & 31;
    nq[(size_t)o * 2048 + p] = pv;           // new_queue head (first 8 cols)
    if (t == 0) {
      const float np = (float)(*nposp);
      outLoss[0] = ((131072.f - np) / 131072.f * lpln[0] + np / 131072.f * lpln[1]) / 131072.f;
    }
  } else {
    const int idx = (g << 8) + t;
    const int o = idx >> 11, j = idx & 2047;
    const float v = objq[idx];
    qt[(j << 5) + o] = f2bf(v);              // bank logits use the OLD queue
    if (j >= 8) nq[idx] = v;
  }
}

// ---- DE: logits. 16 rows/block, FOUR column phases of 512 out-cols
// (buf ~34 KB -> 4 blocks/CU so drain duty averages toward full store pipe),
// XCD-compacting swizzle, NT full-line stores, 2080/2048B-contiguous row
// bursts in address order. Structure per phase: compute -> bar -> drain -> bar
// (the R8-proven separation; R9 showed merging intervals hurts). ----
__global__ __launch_bounds__(256) void kDE(const ushort* __restrict__ qsel, const ushort* __restrict__ qt,
                                           const float* __restrict__ proto, const float* __restrict__ clsel,
                                           const int* __restrict__ salsel,
                                           float* __restrict__ out, int* __restrict__ pl) {
  __shared__ float buf[16][524];    // phase0: cols 0..519 (head 8 + 32 tiles); phases 1-3: 512 cols
  __shared__ float dd[16][9];
  const int t = threadIdx.x;
  const int g = ((blockIdx.x & 7) << 9) + (blockIdx.x >> 3);   // XCD-compacting swizzle
  const int wv = t >> 6, lane = t & 63;
  const int r0 = g << 4;            // 16 rows per block
  if (t < 16) pl[r0 + t] = 0;

  const int rlo = lane & 15, kh = lane >> 4;
  const f32x4 zero = {0.f, 0.f, 0.f, 0.f};

  // B-fragment: the block's 16 q_sel rows (reused in all phases)
  const short8 bfrag = *reinterpret_cast<const short8*>(
      qsel + (size_t)(r0 + rlo) * 32 + kh * 8);
  const ushort* qa = qt + rlo * 32 + kh * 8;
  float* obase = out + (size_t)r0 * NCOLS;

  // head dots: 128 threads, row = t>>3, proto = t&7
  if (t < 128) {
    const int ri = t >> 3, pp = t & 7;
    const short8* qp = reinterpret_cast<const short8*>(qsel + ((size_t)(r0 + ri) << 5));
    float s = 0.f;
#pragma unroll
    for (int i = 0; i < 4; ++i) {
      const short8 v8 = qp[i];
#pragma unroll
      for (int j = 0; j < 8; ++j)
        s = fmaf(proto[(pp << 5) + (i << 3) + j], bf2f((unsigned short)v8[j]), s);
    }
    dd[ri][pp] = s;
  }
  __syncthreads();

  // ---- phase 0: head cols (buf 0..7) + bank tiles 0..31 (buf 8..519) ----
  if (t < 16) {
    const int b = salsel[r0 + t];
    buf[t][0] = clsel[r0 + t] * 2.5f;
#pragma unroll
    for (int c = 0; c < 7; ++c) {
      const int pi = c + ((c >= b) ? 1 : 0);
      buf[t][1 + c] = dd[t][pi] * 2.5f;
    }
  }
#pragma unroll
  for (int ct2 = 0; ct2 < 8; ++ct2) {
    const int lt = (wv << 3) + ct2;          // tile 0..31
    const short8 afrag = *reinterpret_cast<const short8*>(qa + (size_t)lt * 512);
    f32x4 r = __builtin_amdgcn_mfma_f32_16x16x32_bf16(afrag, bfrag, zero, 0, 0, 0);
    r *= 2.5f;
    *reinterpret_cast<f32x4*>(&buf[rlo][8 + (lt << 4) + (kh << 2)]) = r;
  }
  __syncthreads();
  // drain phase 0: 16 rows x 520 cols, address-sequential (row-major flat sweep)
#pragma unroll
  for (int i = 0; i < 9; ++i) {
    const int w4 = (i << 8) + t;
    if (w4 < 2080) {
      const int row = w4 / 130;
      const int c4 = w4 - row * 130;
      const f32x4 v = *reinterpret_cast<const f32x4*>(&buf[row][c4 << 2]);
      __builtin_nontemporal_store(v, reinterpret_cast<f32x4*>(obase + (size_t)row * NCOLS + (c4 << 2)));
    }
  }
  __syncthreads();

  // ---- phases 1..3: bank tiles 32p..32p+31 -> out cols 8+512p .. 519+512p ----
  for (int p = 1; p < 4; ++p) {
#pragma unroll
    for (int ct2 = 0; ct2 < 8; ++ct2) {
      const int lt = (wv << 3) + ct2;        // local tile 0..31
      const short8 afrag = *reinterpret_cast<const short8*>(qa + (size_t)((p << 5) + lt) * 512);
      f32x4 r = __builtin_amdgcn_mfma_f32_16x16x32_bf16(afrag, bfrag, zero, 0, 0, 0);
      r *= 2.5f;
      *reinterpret_cast<f32x4*>(&buf[rlo][(lt << 4) + (kh << 2)]) = r;
    }
    __syncthreads();
    const int cbase = 8 + (p << 9);
#pragma unroll
    for (int i = 0; i < 8; ++i) {
      const int w4 = (i << 8) + t;
      const int row = w4 >> 7;
      const int c4 = w4 & 127;
      const f32x4 v = *reinterpret_cast<const f32x4*>(&buf[row][c4 << 2]);
      __builtin_nontemporal_store(v, reinterpret_cast<f32x4*>(obase + (size_t)row * NCOLS + cbase + (c4 << 2)));
    }
    __syncthreads();
  }
}

extern "C" void kernel_launch(void* const* d_in, const int* in_sizes, int n_in,
                              void* d_out, int out_size, void* d_ws, size_t ws_size,
                              hipStream_t stream) {
  const float* imq  = (const float*)d_in[0];
  const int*   salq = (const int*)d_in[1];
  const float* imk  = (const float*)d_in[2];
  const int*   salk = (const int*)d_in[3];
  const float* Wq   = (const float*)d_in[4];
  const float* Wbg  = (const float*)d_in[5];
  const float* Wk   = (const float*)d_in[6];
  const float* Wcls = (const float*)d_in[7];
  const float* objq = (const float*)d_in[8];
  float* out = (float*)d_out;
  char* ws = (char*)d_ws;

  int*    tileCnt  = (int*)(ws + WS_TILECNT);
  int*    tileBase = (int*)(ws + WS_TILEBASE);
  int*    nposp    = (int*)(ws + WS_NPOS);
  float*  lpln     = (float*)(ws + WS_LPLN);
  float*  wqt      = (float*)(ws + WS_WQT);
  float*  wkmt     = (float*)(ws + WS_WKMT);
  float*  psum     = (float*)(ws + WS_PSUM);
  float*  proto    = (float*)(ws + WS_PROTO);
  ushort* qt       = (ushort*)(ws + WS_QT);
  float*  clsel    = (float*)(ws + WS_CLSEL);
  int*    salsel   = (int*)(ws + WS_SALSEL);
  ushort* qsel     = (ushort*)(ws + WS_QSEL);

  hipLaunchKernelGGL(kP1, dim3(256), dim3(256), 0, stream, salq, tileCnt, Wq, Wk, wqt, wkmt, psum, lpln);
  hipLaunchKernelGGL(kP2, dim3(1), dim3(256), 0, stream, tileCnt, tileBase, nposp);
  hipLaunchKernelGGL(kAB, dim3(512), dim3(256), 0, stream, imq, imk, salq, salk, wqt, wkmt,
                     Wbg, Wcls, tileBase, qsel, clsel, salsel, lpln, psum);
  hipLaunchKernelGGL(kC, dim3(257), dim3(256), 0, stream, objq, psum, lpln, nposp, proto, qt,
                     out + OUT_NQ, out + OUT_LOSS);
  hipLaunchKernelGGL(kDE, dim3(4096), dim3(256), 0, stream, qsel, qt, proto, clsel, salsel,
                     out, (int*)(out + OUT_PL));
}